// Round 4
// baseline (271.541 us; speedup 1.0000x reference)
//
#include <hip/hip_runtime.h>
#include <hip/hip_bf16.h>

#define DEVI __device__ __forceinline__

typedef __bf16 bf16x8 __attribute__((ext_vector_type(8)));
typedef float f32x4 __attribute__((ext_vector_type(4)));
typedef unsigned short u16x8 __attribute__((ext_vector_type(8)));
typedef unsigned short u16x4 __attribute__((ext_vector_type(4)));
typedef unsigned long long ull;

constexpr int Nn = 2, Ss = 2048, Ee = 1024, Hh = 16;
constexpr int Ms = Nn * Ss;                       // 4096 rows
constexpr float SCALE = 0.022097086912079608f;    // 1/sqrt(2048) -- key-length scaling!

// workspace layout (bf16 elements)
constexpr size_t SZ_X   = (size_t)Ms * Ee;        // 4,194,304
constexpr size_t OFF_QB = 0;                      // Q projected [Ms][Ee]
constexpr size_t OFF_KB = SZ_X;                   // K projected [Ms][Ee]
constexpr size_t OFF_VB = 2 * SZ_X;               // V projected TRANSPOSED [Ee][Ms]
constexpr size_t OFF_XQ = 3 * SZ_X;               // bf16 inputs (3)
constexpr size_t OFF_W  = 6 * SZ_X;               // 4 weights, each Ee*Ee
constexpr size_t OFF_PACK = 6 * SZ_X + 4 * (size_t)Ee * Ee;  // bitmask, 67 MB
constexpr size_t OFF_ATTN = OFF_XQ;               // attention out aliases XQ (dead by then)

DEVI unsigned short f2bf(float f) {               // RNE f32->bf16 (no NaN in this data)
  unsigned int u = __builtin_bit_cast(unsigned int, f);
  u += 0x7fffu + ((u >> 16) & 1u);
  return (unsigned short)(u >> 16);
}

DEVI void async16(const void* g, void* l) {
  __builtin_amdgcn_global_load_lds(
      (const __attribute__((address_space(1))) void*)g,
      (__attribute__((address_space(3))) void*)l, 16, 0, 0);
}

DEVI f32x4 mfma_bf16(bf16x8 a, bf16x8 b, f32x4 c) {
  return __builtin_amdgcn_mfma_f32_16x16x32_bf16(a, b, c, 0, 0, 0);
}

// ---------------- fp32 -> bf16 convert, z-batched over up to 4 sources -------------
__global__ __launch_bounds__(256) void cvt_batch(
    const float* __restrict__ s0, const float* __restrict__ s1,
    const float* __restrict__ s2, const float* __restrict__ s3,
    unsigned short* __restrict__ dbase, size_t dstride, int n4)
{
  const float* s = (blockIdx.z == 0) ? s0 : (blockIdx.z == 1) ? s1
                 : (blockIdx.z == 2) ? s2 : s3;
  unsigned short* d = dbase + (size_t)blockIdx.z * dstride;
  const int i = blockIdx.x * 256 + threadIdx.x;
  if (i >= n4) return;
  const float4 v = reinterpret_cast<const float4*>(s)[i];
  u16x4 o = { f2bf(v.x), f2bf(v.y), f2bf(v.z), f2bf(v.w) };
  reinterpret_cast<u16x4*>(d)[i] = o;
}

// ---------------- mask packer: 537 MB int32 -> 16.8 MB bitmask ---------------------
// Pure stream, built to hit HBM BW: 4 coalesced nontemporal dword loads per lane
// per round (stride-64 so each ballot's 64 bits are 64 consecutive k-indices),
// v_cmp + __ballot pack, 8 B store by lanes 0..3. 1024 B in -> 32 B out per round.
__global__ __launch_bounds__(256) void pack_mask(
    const int* __restrict__ mask, ull* __restrict__ P64)
{
  const int lane = threadIdx.x & 63;
  const int gw = (int)((blockIdx.x * 256 + threadIdx.x) >> 6);   // 0..8191
  for (int r = 0; r < 64; ++r) {
    const size_t rgi = (size_t)r * 8192 + gw;      // round-major: contiguous 8MB/round
    const int* mp = mask + rgi * 256 + lane;
    const int m0 = __builtin_nontemporal_load(mp);
    const int m1 = __builtin_nontemporal_load(mp + 64);
    const int m2 = __builtin_nontemporal_load(mp + 128);
    const int m3 = __builtin_nontemporal_load(mp + 192);
    const ull b0 = __ballot(m0 != 0);
    const ull b1 = __ballot(m1 != 0);
    const ull b2 = __ballot(m2 != 0);
    const ull b3 = __ballot(m3 != 0);
    if (lane < 4) {
      const ull v = lane == 0 ? b0 : lane == 1 ? b1 : lane == 2 ? b2 : b3;
      P64[rgi * 4 + lane] = v;
    }
  }
}

// ---------------- 128x128 bf16 GEMM, C = A @ B^T  (A:[M,K=1024], B:[N,K=1024]) -----
// m97 structure: BK=32, global_load_lds width 16, 4 waves each own 64x64.
// ldC parameterized so the V projection can write its output transposed.
template <bool WRITE_F32>
__global__ __launch_bounds__(256) void gemm_bt(
    const unsigned short* __restrict__ Abase,
    const unsigned short* __restrict__ Bbase,
    unsigned short* __restrict__ Cbase,
    float* __restrict__ Cf,
    const float* __restrict__ bias,
    size_t strideA, size_t strideB, size_t strideC, int ldC)
{
  constexpr int K = 1024;
  __shared__ unsigned short As[128 * 32];
  __shared__ unsigned short Bs[128 * 32];

  const int z = blockIdx.z;
  const unsigned short* A = Abase + (size_t)z * strideA;
  const unsigned short* B = Bbase + (size_t)z * strideB;

  const int tid = threadIdx.x;
  const int lane = tid & 63, w = tid >> 6;
  const int lr = lane & 15, lg = lane >> 4;
  const int m0 = blockIdx.y * 128, n0 = blockIdx.x * 128;
  const int wr = (w >> 1) * 64, wc = (w & 1) * 64;

  const f32x4 zero = {0.f, 0.f, 0.f, 0.f};
  f32x4 acc[4][4];
  for (int a = 0; a < 4; ++a)
    for (int b = 0; b < 4; ++b) acc[a][b] = zero;

  for (int k0 = 0; k0 < K; k0 += 32) {
#pragma unroll
    for (int ii = 0; ii < 2; ++ii) {
      const int i = 2 * w + ii;
      const int boff = i * 1024 + lane * 16;     // byte offset in [128][32] bf16 tile
      const int row = boff >> 6;                 // 64 B per row
      const int colb = boff & 63;
      const char* ga = (const char*)A + ((size_t)(m0 + row) * K + k0) * 2 + colb;
      const char* gb = (const char*)B + ((size_t)(n0 + row) * K + k0) * 2 + colb;
      async16(ga, (char*)As + i * 1024);
      async16(gb, (char*)Bs + i * 1024);
    }
    __syncthreads();   // compiler drains vmcnt before s_barrier

    bf16x8 aF[4], bF[4];
#pragma unroll
    for (int rb = 0; rb < 4; ++rb)
      aF[rb] = *(const bf16x8*)(As + (wr + rb * 16 + lr) * 32 + lg * 8);
#pragma unroll
    for (int cb = 0; cb < 4; ++cb)
      bF[cb] = *(const bf16x8*)(Bs + (wc + cb * 16 + lr) * 32 + lg * 8);
#pragma unroll
    for (int rb = 0; rb < 4; ++rb)
#pragma unroll
      for (int cb = 0; cb < 4; ++cb)
        acc[rb][cb] = mfma_bf16(aF[rb], bF[cb], acc[rb][cb]);
    __syncthreads();
  }

#pragma unroll
  for (int rb = 0; rb < 4; ++rb) {
#pragma unroll
    for (int cb = 0; cb < 4; ++cb) {
#pragma unroll
      for (int j = 0; j < 4; ++j) {
        const int row = m0 + wr + rb * 16 + lg * 4 + j;   // C/D: col=lane&15, row=(lane>>4)*4+reg
        const int col = n0 + wc + cb * 16 + lr;
        const float v = acc[rb][cb][j];
        if constexpr (WRITE_F32) {
          Cf[(size_t)row * ldC + col] = v + bias[col];
        } else {
          unsigned short* C = Cbase + (size_t)z * strideC;
          C[(size_t)row * ldC + col] = f2bf(v);
        }
      }
    }
  }
}

// ---------------- fused masked attention (bitmask) ---------------------------------
// Per (n,h): 64 q-rows per block, 4 waves x 16 q-rows. K [k][d] and V^T [d][k] tiles
// staged via global_load_lds into linear [64][64] LDS with XOR-swizzled SOURCE
// (col16 ^= row&7) so ds_read_b128 fragment reads are conflict-free (2-way max).
// Mask comes from the 16.8 MB packed bitmask (L2/L3-resident): 4 x 8 B broadcast
// loads per wave per tile replaces the 537 MB int32 stream.
__global__ __launch_bounds__(256) void attn_kernel(
    const unsigned short* __restrict__ Qb,
    const unsigned short* __restrict__ Kb,     // [Ms][Ee]
    const unsigned short* __restrict__ Vtb,    // [Ee][Ms]  (pre-transposed)
    const ull* __restrict__ P64,               // [Nn*Hh*Ss][32] bit-packed mask
    unsigned short* __restrict__ Ob)
{
  __shared__ unsigned short Kl0[64 * 64], Kl1[64 * 64];
  __shared__ unsigned short Vl0[64 * 64], Vl1[64 * 64];
  __shared__ unsigned short Pl[64 * 72];   // P tile [q][k], pad 72 (2-way max)

  const int tid = threadIdx.x;
  const int lane = tid & 63, w = tid >> 6;
  const int lr = lane & 15, lg = lane >> 4;

  // XCD-locality decode: hardware assigns block lid to XCD (lid % 8).
  const int lid = blockIdx.x;
  const int xcd = lid & 7, slot = lid >> 3;
  const int g = xcd + 8 * (slot >> 5);           // nh group 0..31
  const int n = g >> 4, h = g & 15;
  const int q0 = (slot & 31) * 64;

  // Q fragments: wave w owns q rows [q0+16w, q0+16w+16)
  bf16x8 aQ[2];
  {
    const unsigned short* qp =
        Qb + ((size_t)(n * Ss + q0 + w * 16 + lr)) * Ee + h * 64 + lg * 8;
    aQ[0] = *(const bf16x8*)(qp);
    aQ[1] = *(const bf16x8*)(qp + 32);
  }

  // staging geometry: slot sig = (w*2+ii)*64 + lane covers 16B chunk sig of 8KB tile
  const int sig0 = (w * 2) * 64 + lane;          // issue 0
  const int row0 = sig0 >> 3;
  const int c0 = (sig0 & 7) ^ (row0 & 7);        // pre-swizzled source col16
  const int row1 = row0 + 8;                     // issue 1: sig0+64
  const int c1 = (sig0 & 7) ^ (row1 & 7);
  const int ldsb0 = (w * 2 + 0) * 1024;          // wave-uniform LDS byte base
  const int ldsb1 = (w * 2 + 1) * 1024;

  // element pointers for tile kt=0 (advanced by 64 rows / 64 cols per tile)
  const unsigned short* kp0 = Kb + ((size_t)(n * Ss + row0) * Ee + h * 64 + c0 * 8);
  const unsigned short* kp1 = Kb + ((size_t)(n * Ss + row1) * Ee + h * 64 + c1 * 8);
  const unsigned short* vp0 = Vtb + ((size_t)(h * 64 + row0) * Ms + n * Ss + c0 * 8);
  const unsigned short* vp1 = Vtb + ((size_t)(h * 64 + row1) * Ms + n * Ss + c1 * 8);

  // bitmask row base: row q has 32 ull words; this lane covers rows j=0..3
  const ull* mp = P64 + ((size_t)(n * Hh + h) * Ss + (q0 + w * 16 + lg * 4)) * 32;

  const f32x4 zero = {0.f, 0.f, 0.f, 0.f};
  f32x4 oacc[4] = {zero, zero, zero, zero};
  float rs[4] = {0.f, 0.f, 0.f, 0.f};

  // ---- prologue: stage tile 0 into buf0, mask words for tile 0 into regs ----
  async16(kp0, (char*)Kl0 + ldsb0);
  async16(kp1, (char*)Kl0 + ldsb1);
  async16(vp0, (char*)Vl0 + ldsb0);
  async16(vp1, (char*)Vl0 + ldsb1);
  kp0 += (size_t)64 * Ee; kp1 += (size_t)64 * Ee; vp0 += 64; vp1 += 64;

  uint2 mw[4], mwN[4];
#pragma unroll
  for (int j = 0; j < 4; ++j)
    mw[j] = *(const uint2*)(mp + (size_t)j * 32);

  __syncthreads();

  int cur = 0;
  for (int kt = 0; kt < Ss / 64; ++kt) {
    const unsigned short* Kc = cur ? Kl1 : Kl0;
    const unsigned short* Vc = cur ? Vl1 : Vl0;
    unsigned short* Kn = cur ? Kl0 : Kl1;
    unsigned short* Vn = cur ? Vl0 : Vl1;

    if (kt + 1 < Ss / 64) {
      async16(kp0, (char*)Kn + ldsb0);
      async16(kp1, (char*)Kn + ldsb1);
      async16(vp0, (char*)Vn + ldsb0);
      async16(vp1, (char*)Vn + ldsb1);
      kp0 += (size_t)64 * Ee; kp1 += (size_t)64 * Ee; vp0 += 64; vp1 += 64;
#pragma unroll
      for (int j = 0; j < 4; ++j)
        mwN[j] = *(const uint2*)(mp + (size_t)j * 32 + (kt + 1));
    }

    // S = Q K^T : swizzled read  byte = row*128 + ((kc*4+lg)^(row&7))*16
    f32x4 s4[4];
    __builtin_amdgcn_s_setprio(1);
#pragma unroll
    for (int cb = 0; cb < 4; ++cb) {
      f32x4 a = zero;
#pragma unroll
      for (int kc = 0; kc < 2; ++kc) {
        const int row = cb * 16 + lr;
        bf16x8 bF = *(const bf16x8*)((const char*)Kc + row * 128 +
                                     (((kc * 4 + lg) ^ (row & 7)) * 16));
        a = mfma_bf16(aQ[kc], bF, a);
      }
      s4[cb] = a;
    }
    __builtin_amdgcn_s_setprio(0);

    // P = maskbit ? exp(S*scale) : 0  (logits bounded << 80, no max needed)
#pragma unroll
    for (int cb = 0; cb < 4; ++cb)
#pragma unroll
      for (int j = 0; j < 4; ++j) {
        const int qr = w * 16 + lg * 4 + j;
        const int kk = cb * 16 + lr;
        const unsigned word = (cb & 2) ? mw[j].y : mw[j].x;
        const unsigned bit = (word >> ((cb & 1) * 16 + lr)) & 1u;
        float p = bit ? __expf(s4[cb][j] * SCALE) : 0.f;
        rs[j] += p;
        Pl[qr * 72 + kk] = f2bf(p);
      }

    // O += P V   (P rows wave-private; compiler orders LDS RAW via lgkmcnt)
    bf16x8 aP[2];
    aP[0] = *(const bf16x8*)(Pl + (w * 16 + lr) * 72 + lg * 8);
    aP[1] = *(const bf16x8*)(Pl + (w * 16 + lr) * 72 + 32 + lg * 8);
    __builtin_amdgcn_s_setprio(1);
#pragma unroll
    for (int db = 0; db < 4; ++db)
#pragma unroll
      for (int kc = 0; kc < 2; ++kc) {
        const int row = db * 16 + lr;
        bf16x8 bV = *(const bf16x8*)((const char*)Vc + row * 128 +
                                     (((kc * 4 + lg) ^ (row & 7)) * 16));
        oacc[db] = mfma_bf16(aP[kc], bV, oacc[db]);
      }
    __builtin_amdgcn_s_setprio(0);

    __syncthreads();   // drains staged loads; all waves done reading cur bufs
#pragma unroll
    for (int j = 0; j < 4; ++j) mw[j] = mwN[j];
    cur ^= 1;
  }

  // rowsum reduce across the 16 lanes holding one q-row's k-slices
#pragma unroll
  for (int j = 0; j < 4; ++j) {
    float r = rs[j];
#pragma unroll
    for (int m = 1; m < 16; m <<= 1) r += __shfl_xor(r, m, 64);
    rs[j] = 1.0f / r;
  }
#pragma unroll
  for (int db = 0; db < 4; ++db)
#pragma unroll
    for (int j = 0; j < 4; ++j) {
      const int qr = q0 + w * 16 + lg * 4 + j;
      Ob[((size_t)(n * Ss + qr)) * Ee + h * 64 + db * 16 + lr] =
          f2bf(oacc[db][j] * rs[j]);
    }
}

// -----------------------------------------------------------------------------------
extern "C" void kernel_launch(void* const* d_in, const int* in_sizes, int n_in,
                              void* d_out, int out_size, void* d_ws, size_t ws_size,
                              hipStream_t stream) {
  const float* qin = (const float*)d_in[0];
  const float* kin = (const float*)d_in[1];
  const float* vin = (const float*)d_in[2];
  const int*   msk = (const int*)d_in[3];
  const float* Wq  = (const float*)d_in[4];
  const float* Wk  = (const float*)d_in[5];
  const float* Wv  = (const float*)d_in[6];
  const float* Wo  = (const float*)d_in[7];
  const float* bo  = (const float*)d_in[8];
  unsigned short* ws = (unsigned short*)d_ws;
  ull* P64 = (ull*)(ws + OFF_PACK);
  const size_t EE = (size_t)Ee * Ee;

  // 1) convert inputs + weights to bf16
  cvt_batch<<<dim3((unsigned)(SZ_X / 4 / 256), 1, 3), 256, 0, stream>>>(
      qin, kin, vin, nullptr, ws + OFF_XQ, SZ_X, (int)(SZ_X / 4));
  cvt_batch<<<dim3((unsigned)(EE / 4 / 256), 1, 4), 256, 0, stream>>>(
      Wq, Wk, Wv, Wo, ws + OFF_W, EE, (int)(EE / 4));

  // 2a) Q/K projections (z-batched):  C[m][e] = X @ W^T
  gemm_bt<false><<<dim3(8, 32, 2), 256, 0, stream>>>(
      ws + OFF_XQ, ws + OFF_W, ws + OFF_QB, nullptr, nullptr,
      SZ_X, EE, SZ_X, Ee);

  // 2b) V projection, TRANSPOSED output:  Vt[e][m] = Wv @ Xv^T
  gemm_bt<false><<<dim3(32, 8, 1), 256, 0, stream>>>(
      ws + OFF_W + 2 * EE, ws + OFF_XQ + 2 * SZ_X, ws + OFF_VB, nullptr, nullptr,
      0, 0, 0, Ms);

  // 3a) pack 537 MB int32 mask -> 16.8 MB bitmask (pure HBM stream)
  pack_mask<<<dim3(2048), 256, 0, stream>>>(msk, P64);

  // 3b) masked attention (1D grid, XCD-swizzled, bitmask)
  attn_kernel<<<dim3(1024), 256, 0, stream>>>(
      ws + OFF_QB, ws + OFF_KB, ws + OFF_VB, P64, ws + OFF_ATTN);

  // 4) output projection + bias -> fp32 d_out
  gemm_bt<true><<<dim3(8, 32, 1), 256, 0, stream>>>(
      ws + OFF_ATTN, ws + OFF_W + 3 * EE, nullptr,
      (float*)d_out, bo, 0, 0, 0, Ee);
}

// Round 5
// 241.988 us; speedup vs baseline: 1.1221x; 1.1221x over previous
//
#include <hip/hip_runtime.h>
#include <hip/hip_bf16.h>

#define DEVI __device__ __forceinline__

typedef __bf16 bf16x8 __attribute__((ext_vector_type(8)));
typedef float f32x4 __attribute__((ext_vector_type(4)));
typedef unsigned short u16x8 __attribute__((ext_vector_type(8)));
typedef unsigned short u16x4 __attribute__((ext_vector_type(4)));
typedef unsigned long long ull;

constexpr int Nn = 2, Ss = 2048, Ee = 1024, Hh = 16;
constexpr int Ms = Nn * Ss;                       // 4096 rows
constexpr float SCALE = 0.022097086912079608f;    // 1/sqrt(2048) -- key-length scaling!

// workspace layout (bf16 elements)
constexpr size_t SZ_X   = (size_t)Ms * Ee;        // 4,194,304
constexpr size_t OFF_QB = 0;                      // Q projected [Ms][Ee]
constexpr size_t OFF_KB = SZ_X;                   // K projected [Ms][Ee]
constexpr size_t OFF_VB = 2 * SZ_X;               // V projected TRANSPOSED [Ee][Ms]
constexpr size_t OFF_XQ = 3 * SZ_X;               // bf16 inputs (3)
constexpr size_t OFF_W  = 6 * SZ_X;               // 4 weights, each Ee*Ee
constexpr size_t OFF_ATTN = OFF_XQ;               // attention out aliases XQ (dead by then)

DEVI unsigned short f2bf(float f) {               // RNE f32->bf16 (no NaN in this data)
  unsigned int u = __builtin_bit_cast(unsigned int, f);
  u += 0x7fffu + ((u >> 16) & 1u);
  return (unsigned short)(u >> 16);
}

DEVI void async16(const void* g, void* l) {
  __builtin_amdgcn_global_load_lds(
      (const __attribute__((address_space(1))) void*)g,
      (__attribute__((address_space(3))) void*)l, 16, 0, 0);
}

DEVI f32x4 mfma_bf16(bf16x8 a, bf16x8 b, f32x4 c) {
  return __builtin_amdgcn_mfma_f32_16x16x32_bf16(a, b, c, 0, 0, 0);
}

// ---------------- fp32 -> bf16 convert, z-batched over up to 4 sources -------------
__global__ __launch_bounds__(256) void cvt_batch(
    const float* __restrict__ s0, const float* __restrict__ s1,
    const float* __restrict__ s2, const float* __restrict__ s3,
    unsigned short* __restrict__ dbase, size_t dstride, int n4)
{
  const float* s = (blockIdx.z == 0) ? s0 : (blockIdx.z == 1) ? s1
                 : (blockIdx.z == 2) ? s2 : s3;
  unsigned short* d = dbase + (size_t)blockIdx.z * dstride;
  const int i = blockIdx.x * 256 + threadIdx.x;
  if (i >= n4) return;
  const float4 v = reinterpret_cast<const float4*>(s)[i];
  u16x4 o = { f2bf(v.x), f2bf(v.y), f2bf(v.z), f2bf(v.w) };
  reinterpret_cast<u16x4*>(d)[i] = o;
}

// ---------------- 128x128 bf16 GEMM, C = A @ B^T  (A:[M,K=1024], B:[N,K=1024]) -----
// m97 structure: BK=32, global_load_lds width 16, 4 waves each own 64x64.
// ldC parameterized so the V projection can write its output transposed.
template <bool WRITE_F32>
__global__ __launch_bounds__(256) void gemm_bt(
    const unsigned short* __restrict__ Abase,
    const unsigned short* __restrict__ Bbase,
    unsigned short* __restrict__ Cbase,
    float* __restrict__ Cf,
    const float* __restrict__ bias,
    size_t strideA, size_t strideB, size_t strideC, int ldC)
{
  constexpr int K = 1024;
  __shared__ unsigned short As[128 * 32];
  __shared__ unsigned short Bs[128 * 32];

  const int z = blockIdx.z;
  const unsigned short* A = Abase + (size_t)z * strideA;
  const unsigned short* B = Bbase + (size_t)z * strideB;

  const int tid = threadIdx.x;
  const int lane = tid & 63, w = tid >> 6;
  const int lr = lane & 15, lg = lane >> 4;
  const int m0 = blockIdx.y * 128, n0 = blockIdx.x * 128;
  const int wr = (w >> 1) * 64, wc = (w & 1) * 64;

  const f32x4 zero = {0.f, 0.f, 0.f, 0.f};
  f32x4 acc[4][4];
  for (int a = 0; a < 4; ++a)
    for (int b = 0; b < 4; ++b) acc[a][b] = zero;

  for (int k0 = 0; k0 < K; k0 += 32) {
#pragma unroll
    for (int ii = 0; ii < 2; ++ii) {
      const int i = 2 * w + ii;
      const int boff = i * 1024 + lane * 16;     // byte offset in [128][32] bf16 tile
      const int row = boff >> 6;                 // 64 B per row
      const int colb = boff & 63;
      const char* ga = (const char*)A + ((size_t)(m0 + row) * K + k0) * 2 + colb;
      const char* gb = (const char*)B + ((size_t)(n0 + row) * K + k0) * 2 + colb;
      async16(ga, (char*)As + i * 1024);
      async16(gb, (char*)Bs + i * 1024);
    }
    __syncthreads();   // compiler drains vmcnt before s_barrier

    bf16x8 aF[4], bF[4];
#pragma unroll
    for (int rb = 0; rb < 4; ++rb)
      aF[rb] = *(const bf16x8*)(As + (wr + rb * 16 + lr) * 32 + lg * 8);
#pragma unroll
    for (int cb = 0; cb < 4; ++cb)
      bF[cb] = *(const bf16x8*)(Bs + (wc + cb * 16 + lr) * 32 + lg * 8);
#pragma unroll
    for (int rb = 0; rb < 4; ++rb)
#pragma unroll
      for (int cb = 0; cb < 4; ++cb)
        acc[rb][cb] = mfma_bf16(aF[rb], bF[cb], acc[rb][cb]);
    __syncthreads();
  }

#pragma unroll
  for (int rb = 0; rb < 4; ++rb) {
#pragma unroll
    for (int cb = 0; cb < 4; ++cb) {
#pragma unroll
      for (int j = 0; j < 4; ++j) {
        const int row = m0 + wr + rb * 16 + lg * 4 + j;   // C/D: col=lane&15, row=(lane>>4)*4+reg
        const int col = n0 + wc + cb * 16 + lr;
        const float v = acc[rb][cb][j];
        if constexpr (WRITE_F32) {
          Cf[(size_t)row * ldC + col] = v + bias[col];
        } else {
          unsigned short* C = Cbase + (size_t)z * strideC;
          C[(size_t)row * ldC + col] = f2bf(v);
        }
      }
    }
  }
}

// ---------------- fused masked attention -------------------------------------------
// 128 q-rows per block (4 waves x 32 q-rows), 64-k tiles. K [k][d] and V^T [d][k]
// staged via global_load_lds into linear [64][64] LDS with XOR-swizzled SOURCE
// (col16 ^= row&7) -> conflict-free ds_read_b128. Raw s_barrier + manual vmcnt(0)
// at iteration TOP (no compiler vmcnt(0)-drain mid-pipeline): stage(t+1) and mask
// loads for t+1 stay in flight a full iteration. Mask is consumed via a per-lane
// 32-bit compress right after arrival, freeing prefetch VGPRs immediately.
__global__ __launch_bounds__(256) void attn_kernel(
    const unsigned short* __restrict__ Qb,
    const unsigned short* __restrict__ Kb,     // [Ms][Ee]
    const unsigned short* __restrict__ Vtb,    // [Ee][Ms]  (pre-transposed)
    const int* __restrict__ mask,
    unsigned short* __restrict__ Ob)
{
  __shared__ unsigned short Kl0[64 * 64], Kl1[64 * 64];
  __shared__ unsigned short Vl0[64 * 64], Vl1[64 * 64];
  __shared__ unsigned short Pl[128 * 72];  // P tile [q][k], pad 72 (2-way max)

  const int tid = threadIdx.x;
  const int lane = tid & 63, w = tid >> 6;
  const int lr = lane & 15, lg = lane >> 4;

  // XCD-locality decode: block lid -> XCD (lid % 8). XCD x owns nh-groups
  // {x, x+8, x+16, x+24}; 16 q-blocks (of 128 rows) per group.
  const int lid = blockIdx.x;
  const int xcd = lid & 7, slot = lid >> 3;
  const int g = xcd + 8 * (slot >> 4);           // nh group 0..31
  const int n = g >> 4, h = g & 15;
  const int q0 = (slot & 15) * 128;

  // Q fragments: wave w owns q rows [q0+32w, q0+32w+32)
  bf16x8 aQ[2][2];
#pragma unroll
  for (int qb = 0; qb < 2; ++qb) {
    const unsigned short* qp =
        Qb + ((size_t)(n * Ss + q0 + w * 32 + qb * 16 + lr)) * Ee + h * 64 + lg * 8;
    aQ[qb][0] = *(const bf16x8*)(qp);
    aQ[qb][1] = *(const bf16x8*)(qp + 32);
  }

  // staging geometry: slot sig covers 16B chunk of the 8KB [64][64] tile
  const int sig0 = (w * 2) * 64 + lane;
  const int row0 = sig0 >> 3;
  const int c0 = (sig0 & 7) ^ (row0 & 7);        // pre-swizzled source col16
  const int row1 = row0 + 8;
  const int c1 = (sig0 & 7) ^ (row1 & 7);
  const int ldsb0 = (w * 2 + 0) * 1024;          // wave-uniform LDS byte base
  const int ldsb1 = (w * 2 + 1) * 1024;

  const unsigned short* kp0 = Kb + ((size_t)(n * Ss + row0) * Ee + h * 64 + c0 * 8);
  const unsigned short* kp1 = Kb + ((size_t)(n * Ss + row1) * Ee + h * 64 + c1 * 8);
  const unsigned short* vp0 = Vtb + ((size_t)(h * 64 + row0) * Ms + n * Ss + c0 * 8);
  const unsigned short* vp1 = Vtb + ((size_t)(h * 64 + row1) * Ms + n * Ss + c1 * 8);

  // mask base for this lane: rows q0+32w+lg*4 (+j, +16 per qb), col lr (+16 per cb)
  const int* mp = mask + ((size_t)(n * Hh + h)) * Ss * Ss
                       + (size_t)(q0 + w * 32 + lg * 4) * Ss + lr;

  const f32x4 zero = {0.f, 0.f, 0.f, 0.f};
  f32x4 oacc[2][4];
#pragma unroll
  for (int qb = 0; qb < 2; ++qb)
#pragma unroll
    for (int db = 0; db < 4; ++db) oacc[qb][db] = zero;
  float rs[2][4] = {{0.f, 0.f, 0.f, 0.f}, {0.f, 0.f, 0.f, 0.f}};

  // ---- prologue: stage tile 0 into buf0, mask tile 0 into regs ----
  async16(kp0, (char*)Kl0 + ldsb0);
  async16(kp1, (char*)Kl0 + ldsb1);
  async16(vp0, (char*)Vl0 + ldsb0);
  async16(vp1, (char*)Vl0 + ldsb1);
  kp0 += (size_t)64 * Ee; kp1 += (size_t)64 * Ee; vp0 += 64; vp1 += 64;

  int mv[2][4][4];
#pragma unroll
  for (int qb = 0; qb < 2; ++qb)
#pragma unroll
    for (int j = 0; j < 4; ++j)
#pragma unroll
      for (int cb = 0; cb < 4; ++cb)
        mv[qb][j][cb] = __builtin_nontemporal_load(
            mp + (size_t)(qb * 16 + j) * Ss + cb * 16);

  int cur = 0;
  for (int kt = 0; kt < Ss / 64; ++kt) {
    // everything issued last iteration (stage(kt), mask(kt)) has landed; waves sync
    asm volatile("s_waitcnt vmcnt(0)" ::: "memory");
    __builtin_amdgcn_s_barrier();

    const unsigned short* Kc = cur ? Kl1 : Kl0;
    const unsigned short* Vc = cur ? Vl1 : Vl0;
    unsigned short* Kn = cur ? Kl0 : Kl1;
    unsigned short* Vn = cur ? Vl0 : Vl1;

    // compress mask(kt) to one bit per (qb,j,cb) -> frees mv regs for reissue
    unsigned mbits = 0;
#pragma unroll
    for (int qb = 0; qb < 2; ++qb)
#pragma unroll
      for (int j = 0; j < 4; ++j)
#pragma unroll
        for (int cb = 0; cb < 4; ++cb)
          mbits |= (mv[qb][j][cb] != 0 ? 1u : 0u) << (((qb * 4 + j) * 4) + cb);

    if (kt + 1 < Ss / 64) {
      // issue next tile's staging + mask prefetch: in flight until next iter top
      async16(kp0, (char*)Kn + ldsb0);
      async16(kp1, (char*)Kn + ldsb1);
      async16(vp0, (char*)Vn + ldsb0);
      async16(vp1, (char*)Vn + ldsb1);
      kp0 += (size_t)64 * Ee; kp1 += (size_t)64 * Ee; vp0 += 64; vp1 += 64;
#pragma unroll
      for (int qb = 0; qb < 2; ++qb)
#pragma unroll
        for (int j = 0; j < 4; ++j)
#pragma unroll
          for (int cb = 0; cb < 4; ++cb)
            mv[qb][j][cb] = __builtin_nontemporal_load(
                mp + (size_t)(qb * 16 + j) * Ss + (size_t)(kt + 1) * 64 + cb * 16);
    }

    // per q-block: S = Q K^T, then softmax into Pl (limits live s4 regs)
#pragma unroll
    for (int qb = 0; qb < 2; ++qb) {
      f32x4 s4[4];
      __builtin_amdgcn_s_setprio(1);
#pragma unroll
      for (int cb = 0; cb < 4; ++cb) {
        f32x4 a = zero;
#pragma unroll
        for (int kc = 0; kc < 2; ++kc) {
          const int row = cb * 16 + lr;
          bf16x8 bF = *(const bf16x8*)((const char*)Kc + row * 128 +
                                       (((kc * 4 + lg) ^ (row & 7)) * 16));
          a = mfma_bf16(aQ[qb][kc], bF, a);
        }
        s4[cb] = a;
      }
      __builtin_amdgcn_s_setprio(0);

#pragma unroll
      for (int cb = 0; cb < 4; ++cb)
#pragma unroll
        for (int j = 0; j < 4; ++j) {
          const int qr = w * 32 + qb * 16 + lg * 4 + j;
          const int kk = cb * 16 + lr;
          const unsigned bit = (mbits >> (((qb * 4 + j) * 4) + cb)) & 1u;
          float p = bit ? __expf(s4[cb][j] * SCALE) : 0.f;
          rs[qb][j] += p;
          Pl[qr * 72 + kk] = f2bf(p);
        }
    }

    // O += P V   (Pl rows wave-private; compiler orders LDS RAW via lgkmcnt)
    bf16x8 aP[2][2];
#pragma unroll
    for (int qb = 0; qb < 2; ++qb) {
      aP[qb][0] = *(const bf16x8*)(Pl + (w * 32 + qb * 16 + lr) * 72 + lg * 8);
      aP[qb][1] = *(const bf16x8*)(Pl + (w * 32 + qb * 16 + lr) * 72 + 32 + lg * 8);
    }
    __builtin_amdgcn_s_setprio(1);
#pragma unroll
    for (int db = 0; db < 4; ++db) {
      const int row = db * 16 + lr;
#pragma unroll
      for (int kc = 0; kc < 2; ++kc) {
        bf16x8 bV = *(const bf16x8*)((const char*)Vc + row * 128 +
                                     (((kc * 4 + lg) ^ (row & 7)) * 16));
#pragma unroll
        for (int qb = 0; qb < 2; ++qb)
          oacc[qb][db] = mfma_bf16(aP[qb][kc], bV, oacc[qb][db]);
      }
    }
    __builtin_amdgcn_s_setprio(0);

    cur ^= 1;
  }

  // rowsum reduce across the 16 lanes holding one q-row's k-slices
#pragma unroll
  for (int qb = 0; qb < 2; ++qb)
#pragma unroll
    for (int j = 0; j < 4; ++j) {
      float r = rs[qb][j];
#pragma unroll
      for (int m = 1; m < 16; m <<= 1) r += __shfl_xor(r, m, 64);
      rs[qb][j] = 1.0f / r;
    }
#pragma unroll
  for (int qb = 0; qb < 2; ++qb)
#pragma unroll
    for (int db = 0; db < 4; ++db)
#pragma unroll
      for (int j = 0; j < 4; ++j) {
        const int qr = q0 + w * 32 + qb * 16 + lg * 4 + j;
        Ob[((size_t)(n * Ss + qr)) * Ee + h * 64 + db * 16 + lr] =
            f2bf(oacc[qb][db][j] * rs[qb][j]);
      }
}

// -----------------------------------------------------------------------------------
extern "C" void kernel_launch(void* const* d_in, const int* in_sizes, int n_in,
                              void* d_out, int out_size, void* d_ws, size_t ws_size,
                              hipStream_t stream) {
  const float* qin = (const float*)d_in[0];
  const float* kin = (const float*)d_in[1];
  const float* vin = (const float*)d_in[2];
  const int*   msk = (const int*)d_in[3];
  const float* Wq  = (const float*)d_in[4];
  const float* Wk  = (const float*)d_in[5];
  const float* Wv  = (const float*)d_in[6];
  const float* Wo  = (const float*)d_in[7];
  const float* bo  = (const float*)d_in[8];
  unsigned short* ws = (unsigned short*)d_ws;
  const size_t EE = (size_t)Ee * Ee;

  // 1) convert inputs + weights to bf16
  cvt_batch<<<dim3((unsigned)(SZ_X / 4 / 256), 1, 3), 256, 0, stream>>>(
      qin, kin, vin, nullptr, ws + OFF_XQ, SZ_X, (int)(SZ_X / 4));
  cvt_batch<<<dim3((unsigned)(EE / 4 / 256), 1, 4), 256, 0, stream>>>(
      Wq, Wk, Wv, Wo, ws + OFF_W, EE, (int)(EE / 4));

  // 2a) Q/K projections (z-batched):  C[m][e] = X @ W^T
  gemm_bt<false><<<dim3(8, 32, 2), 256, 0, stream>>>(
      ws + OFF_XQ, ws + OFF_W, ws + OFF_QB, nullptr, nullptr,
      SZ_X, EE, SZ_X, Ee);

  // 2b) V projection, TRANSPOSED output:  Vt[e][m] = Wv @ Xv^T
  gemm_bt<false><<<dim3(32, 8, 1), 256, 0, stream>>>(
      ws + OFF_W + 2 * EE, ws + OFF_XQ + 2 * SZ_X, ws + OFF_VB, nullptr, nullptr,
      0, 0, 0, Ms);

  // 3) masked attention (1D grid 512, XCD-swizzled, inline int32 mask)
  attn_kernel<<<dim3(512), 256, 0, stream>>>(
      ws + OFF_QB, ws + OFF_KB, ws + OFF_VB, msk, ws + OFF_ATTN);

  // 4) output projection + bias -> fp32 d_out
  gemm_bt<true><<<dim3(8, 32, 1), 256, 0, stream>>>(
      ws + OFF_ATTN, ws + OFF_W + 3 * EE, nullptr,
      (float*)d_out, bo, 0, 0, 0, Ee);
}